// Round 4
// baseline (29047.870 us; speedup 1.0000x reference)
//
#include <hip/hip_runtime.h>
#include <hip/hip_cooperative_groups.h>
#include <math.h>

// Problem constants
#define SS 256   // encoder seq len
#define BB 256   // batch
#define HH 512   // hidden
#define OO 64    // output dim
#define NSTEP 63 // only outs[:63] are used

namespace cg = cooperative_groups;

// ---------------------------------------------------------------------------
// K0: EW = enc @ Wa_bot  (M=65536, K=512, N=512), fp32, 128x128 tile.
// Output relayout: row m = s*256+b  ->  EW[b][s][h]  (contiguous per batch b)
// ---------------------------------------------------------------------------
__global__ __launch_bounds__(256) void k_ew_gemm(const float* __restrict__ A,
                                                 const float* __restrict__ Bm,
                                                 float* __restrict__ C)
{
    __shared__ float As[8][132];
    __shared__ float Bs[8][132];
    const int tid = threadIdx.x;
    const int bm = blockIdx.x * 128;
    const int bn = blockIdx.y * 128;
    const int tx = tid & 15;
    const int ty = tid >> 4;
    const int a_row = tid >> 1;
    const int a_k4 = (tid & 1) * 4;
    const int b_row = tid >> 5;
    const int b_n4 = (tid & 31) * 4;

    float acc[8][8];
#pragma unroll
    for (int i = 0; i < 8; i++)
#pragma unroll
        for (int j = 0; j < 8; j++) acc[i][j] = 0.f;

    for (int kt = 0; kt < 512; kt += 8) {
        float4 av = *(const float4*)(A + (size_t)(bm + a_row) * 512 + kt + a_k4);
        As[a_k4 + 0][a_row] = av.x;
        As[a_k4 + 1][a_row] = av.y;
        As[a_k4 + 2][a_row] = av.z;
        As[a_k4 + 3][a_row] = av.w;
        *(float4*)(&Bs[b_row][b_n4]) = *(const float4*)(Bm + (size_t)(kt + b_row) * 512 + bn + b_n4);
        __syncthreads();
#pragma unroll
        for (int kk = 0; kk < 8; kk++) {
            float av8[8], bv8[8];
            *(float4*)&av8[0] = *(const float4*)&As[kk][ty * 4];
            *(float4*)&av8[4] = *(const float4*)&As[kk][64 + ty * 4];
            *(float4*)&bv8[0] = *(const float4*)&Bs[kk][tx * 4];
            *(float4*)&bv8[4] = *(const float4*)&Bs[kk][64 + tx * 4];
#pragma unroll
            for (int i = 0; i < 8; i++)
#pragma unroll
                for (int j = 0; j < 8; j++) acc[i][j] += av8[i] * bv8[j];
        }
        __syncthreads();
    }
#pragma unroll
    for (int i = 0; i < 8; i++) {
        int m = bm + ((i < 4) ? (ty * 4 + i) : (64 + ty * 4 + i - 4));
        int mrow = (m & 255) * 256 + (m >> 8);   // [b][s] relayout
        float4 o0 = make_float4(acc[i][0], acc[i][1], acc[i][2], acc[i][3]);
        float4 o1 = make_float4(acc[i][4], acc[i][5], acc[i][6], acc[i][7]);
        *(float4*)(C + (size_t)mrow * 512 + bn + tx * 4) = o0;
        *(float4*)(C + (size_t)mrow * 512 + bn + 64 + tx * 4) = o1;
    }
}

// ---------------------------------------------------------------------------
// q init: qpre = h0 @ Wa_top   (no bias; ba deferred to attn phase)
// ---------------------------------------------------------------------------
__global__ __launch_bounds__(256) void k_qinit(const float* __restrict__ A,
                                               const float* __restrict__ Wa,
                                               float* __restrict__ qpre)
{
    __shared__ float As[32][33];
    __shared__ float Bs[32][33];
    const int tid = threadIdx.x;
    const int bn = blockIdx.x * 32;
    const int bm = blockIdx.y * 32;
    const int tx = tid & 15;
    const int ty = tid >> 4;
    const int l_row = tid >> 3;
    const int l_c4 = (tid & 7) * 4;

    float acc00 = 0.f, acc01 = 0.f, acc10 = 0.f, acc11 = 0.f;
    for (int kt = 0; kt < 512; kt += 32) {
#pragma unroll
        for (int i = 0; i < 4; i++)
            As[l_c4 + i][l_row] = A[(size_t)(bm + l_row) * 512 + kt + l_c4 + i];
#pragma unroll
        for (int i = 0; i < 4; i++)
            Bs[l_row][l_c4 + i] = Wa[(size_t)(kt + l_row) * 512 + bn + l_c4 + i];
        __syncthreads();
#pragma unroll
        for (int kk = 0; kk < 32; kk++) {
            float a0 = As[kk][ty * 2], a1 = As[kk][ty * 2 + 1];
            float b0 = Bs[kk][tx * 2], b1 = Bs[kk][tx * 2 + 1];
            acc00 += a0 * b0; acc01 += a0 * b1;
            acc10 += a1 * b0; acc11 += a1 * b1;
        }
        __syncthreads();
    }
    qpre[(size_t)(bm + ty * 2) * 512 + bn + tx * 2]     = acc00;
    qpre[(size_t)(bm + ty * 2) * 512 + bn + tx * 2 + 1] = acc01;
    qpre[(size_t)(bm + ty * 2 + 1) * 512 + bn + tx * 2]     = acc10;
    qpre[(size_t)(bm + ty * 2 + 1) * 512 + bn + tx * 2 + 1] = acc11;
}

// ---------------------------------------------------------------------------
// k_loop: persistent cooperative kernel for all 63 decode steps.
// 256 blocks x 1024 threads (1 block/CU, 16 waves). Per step:
//   A: attention for batch b=blk (round-2-proven body) + prev-step argmax
//   B: h = tanh([x|ctx|h_prev] @ [W_ih|W_hh]^T + b_ih + b_hh)  (no atomics)
//   C: ob = h@Wo^T ; qpre = h@Wa_top                            (no atomics)
// grid.sync() between phases. All math fp32 + libm tanhf.
// ---------------------------------------------------------------------------
__global__ __launch_bounds__(1024) void k_loop(
    const float* __restrict__ EW, const float* __restrict__ enc,
    float* __restrict__ qpre, const float* __restrict__ ba,
    const float* __restrict__ vvec, float* __restrict__ ctx,
    const float* __restrict__ h0, const float* __restrict__ sos,
    float* __restrict__ xb, float* __restrict__ hb0, float* __restrict__ hb1,
    const float* __restrict__ W_ih, const float* __restrict__ W_hh,
    const float* __restrict__ b_ih, const float* __restrict__ b_hh,
    const float* __restrict__ Wo, const float* __restrict__ Wa,
    const float* __restrict__ bo, float* __restrict__ ob,
    float* __restrict__ dout)
{
    cg::grid_group grid = cg::this_grid();
    __shared__ float smem[9488];
    const int blk = blockIdx.x;
    const int tid = threadIdx.x;

    for (int t = 0; t < NSTEP; t++) {
        const float* hprev = (t == 0) ? h0 : ((t & 1) ? hb0 : hb1);
        float* hcur = (t & 1) ? hb1 : hb0;
        const float* xin = (t == 0) ? sos : xb;

        // ================= phase A: attention (block = batch b) =============
        {
            const int b = blk;
            float* qs   = smem;            // 512
            float* vs   = smem + 512;      // 512
            float* sc   = smem + 1024;     // 256
            float* red  = smem + 1280;     // 16
            float* ctxp = smem + 1296;     // 16*512

            // prev-step argmax + dout (ob complete & synced from phase C)
            if (t > 0 && tid < 64) {
                const int l = tid;
                float v = ob[b * 64 + l] + bo[l];
                dout[(size_t)b * (OO * NSTEP) + l * NSTEP + (t - 1)] = v;
                int bi = l;
                float bv = v;
#pragma unroll
                for (int off = 1; off < 64; off <<= 1) {
                    float ov = __shfl_xor(bv, off);
                    int oi = __shfl_xor(bi, off);
                    if (ov > bv || (ov == bv && oi < bi)) { bv = ov; bi = oi; }
                }
                xb[b * 64 + l] = (l == bi) ? 1.0f : 0.0f;
            }

            if (tid < 512) {
                qs[tid] = qpre[b * 512 + tid] + ba[tid];
                vs[tid] = vvec[tid];
            }
            __syncthreads();

            const int w = tid >> 6;    // 0..15
            const int l = tid & 63;

            float qv[8], vv[8];
            *(float4*)&qv[0] = *(const float4*)&qs[l * 8];
            *(float4*)&qv[4] = *(const float4*)&qs[l * 8 + 4];
            *(float4*)&vv[0] = *(const float4*)&vs[l * 8];
            *(float4*)&vv[4] = *(const float4*)&vs[l * 8 + 4];

            // scores (wave w: s = w*16 .. w*16+15, 2-way unrolled)
            {
                const float4* pe = (const float4*)(EW + ((size_t)b * 256 + w * 16) * 512);
                for (int i = 0; i < 16; i += 2) {
                    float4 e00 = pe[(size_t)i * 128 + 2 * l];
                    float4 e01 = pe[(size_t)i * 128 + 2 * l + 1];
                    float4 e10 = pe[(size_t)(i + 1) * 128 + 2 * l];
                    float4 e11 = pe[(size_t)(i + 1) * 128 + 2 * l + 1];
                    float a0, a1;
                    a0  = vv[0] * tanhf(e00.x + qv[0]);
                    a0 += vv[1] * tanhf(e00.y + qv[1]);
                    a0 += vv[2] * tanhf(e00.z + qv[2]);
                    a0 += vv[3] * tanhf(e00.w + qv[3]);
                    a0 += vv[4] * tanhf(e01.x + qv[4]);
                    a0 += vv[5] * tanhf(e01.y + qv[5]);
                    a0 += vv[6] * tanhf(e01.z + qv[6]);
                    a0 += vv[7] * tanhf(e01.w + qv[7]);
                    a1  = vv[0] * tanhf(e10.x + qv[0]);
                    a1 += vv[1] * tanhf(e10.y + qv[1]);
                    a1 += vv[2] * tanhf(e10.z + qv[2]);
                    a1 += vv[3] * tanhf(e10.w + qv[3]);
                    a1 += vv[4] * tanhf(e11.x + qv[4]);
                    a1 += vv[5] * tanhf(e11.y + qv[5]);
                    a1 += vv[6] * tanhf(e11.z + qv[6]);
                    a1 += vv[7] * tanhf(e11.w + qv[7]);
#pragma unroll
                    for (int off = 32; off; off >>= 1) {
                        a0 += __shfl_down(a0, off);
                        a1 += __shfl_down(a1, off);
                    }
                    if (l == 0) {
                        sc[w * 16 + i]     = a0;
                        sc[w * 16 + i + 1] = a1;
                    }
                }
            }
            __syncthreads();

            // softmax over s (waves 0-3)
            if (tid < 256) {
                float m = sc[tid];
#pragma unroll
                for (int off = 32; off; off >>= 1) m = fmaxf(m, __shfl_down(m, off));
                if ((tid & 63) == 0) red[tid >> 6] = m;
            }
            __syncthreads();
            if (tid < 256) {
                float mx = fmaxf(fmaxf(red[0], red[1]), fmaxf(red[2], red[3]));
                float e = expf(sc[tid] - mx);
                sc[tid] = e;
                float ssum = e;
#pragma unroll
                for (int off = 32; off; off >>= 1) ssum += __shfl_down(ssum, off);
                if ((tid & 63) == 0) red[8 + (tid >> 6)] = ssum;
            }
            __syncthreads();
            const float inv = 1.0f / (red[8] + red[9] + red[10] + red[11]);

            // partial context (wave w: s = w*16 .. w*16+15)
            {
                float c[8];
#pragma unroll
                for (int j = 0; j < 8; j++) c[j] = 0.f;
                for (int i = 0; i < 16; i += 2) {
                    int s0 = w * 16 + i;
                    int s1 = s0 + 1;
                    float w0 = sc[s0];
                    float w1 = sc[s1];
                    const float4* p0 = (const float4*)(enc + ((size_t)s0 * 256 + b) * 512);
                    const float4* p1 = (const float4*)(enc + ((size_t)s1 * 256 + b) * 512);
                    float4 e00 = p0[2 * l];
                    float4 e01 = p0[2 * l + 1];
                    float4 e10 = p1[2 * l];
                    float4 e11 = p1[2 * l + 1];
                    c[0] += w0 * e00.x; c[1] += w0 * e00.y;
                    c[2] += w0 * e00.z; c[3] += w0 * e00.w;
                    c[4] += w0 * e01.x; c[5] += w0 * e01.y;
                    c[6] += w0 * e01.z; c[7] += w0 * e01.w;
                    c[0] += w1 * e10.x; c[1] += w1 * e10.y;
                    c[2] += w1 * e10.z; c[3] += w1 * e10.w;
                    c[4] += w1 * e11.x; c[5] += w1 * e11.y;
                    c[6] += w1 * e11.z; c[7] += w1 * e11.w;
                }
                float4 c0 = make_float4(c[0], c[1], c[2], c[3]);
                float4 c1 = make_float4(c[4], c[5], c[6], c[7]);
                *(float4*)&ctxp[w * 512 + l * 8]     = c0;
                *(float4*)&ctxp[w * 512 + l * 8 + 4] = c1;
            }
            __syncthreads();
            if (tid < 512) {
                float r = 0.f;
#pragma unroll
                for (int g = 0; g < 16; g++) r += ctxp[g * 512 + tid];
                ctx[b * 512 + tid] = r * inv;
            }
        }
        __threadfence();
        grid.sync();

        // ================= phase B: h-GEMM (16mt x 16nt, tile 16m x 32n) ====
        {
            const int mt = blk >> 4, nt = blk & 15;
            const int m0 = mt * 16, n0 = nt * 32;
            float* As  = smem;           // [64][17] = 1088
            float* Bs  = smem + 1088;    // [64][33] = 2112
            float* red = smem + 3200;    // 512
            const int am = tid >> 6, ak = tid & 63;
            const int o = tid & 511, kh = tid >> 9;
            const int om = o >> 5, on = o & 31;
            float acc = 0.f;

            for (int c = 0; c < 17; c++) {
                const int k0 = c * 64;
                __syncthreads();
                // stage A (16m x 64k): virtual [x | ctx | h_prev]
                {
                    int k = k0 + ak, m = m0 + am;
                    float v;
                    if (k < 64) v = xin[m * 64 + k];
                    else if (k < 576) v = ctx[m * 512 + (k - 64)];
                    else v = hprev[m * 512 + (k - 576)];
                    As[ak * 17 + am] = v;
                }
                // stage B (32n x 64k): [W_ih | W_hh] row n
#pragma unroll
                for (int it = 0; it < 2; it++) {
                    int j = tid + it * 1024;
                    int n = j >> 6, kk = j & 63;
                    int k = k0 + kk, ng = n0 + n;
                    float v = (k < 576) ? W_ih[(size_t)ng * 576 + k]
                                        : W_hh[(size_t)ng * 512 + (k - 576)];
                    Bs[kk * 33 + n] = v;
                }
                __syncthreads();
#pragma unroll
                for (int kk2 = 0; kk2 < 32; kk2++) {
                    int kk = kh * 32 + kk2;
                    acc += As[kk * 17 + om] * Bs[kk * 33 + on];
                }
            }
            __syncthreads();
            if (kh == 1) red[o] = acc;
            __syncthreads();
            if (kh == 0) {
                int ng = n0 + on, mg = m0 + om;
                float s = acc + red[o];
                hcur[mg * 512 + ng] = tanhf(s + b_ih[ng] + b_hh[ng]);
            }
        }
        __threadfence();
        grid.sync();

        // ================= phase C: ob/qpre GEMM (16mt x 9nt, 16m x 64n) ====
        {
            if (blk < 144) {
                const int mt = blk / 9, nt = blk % 9;
                const int m0 = mt * 16, n0 = nt * 64;
                float* As = smem;          // [64][17] = 1088
                float* Bs = smem + 1088;   // [64][65] = 4160
                const int am = tid >> 6, ak = tid & 63;
                const int om = tid >> 6, on = tid & 63;
                float acc = 0.f;

                for (int c = 0; c < 8; c++) {
                    const int k0 = c * 64;
                    __syncthreads();
                    As[ak * 17 + am] = hcur[(m0 + am) * 512 + k0 + ak];
                    if (nt == 0) {
#pragma unroll
                        for (int it = 0; it < 4; it++) {
                            int j = tid + it * 1024;
                            int n = j >> 6, kk = j & 63;
                            Bs[kk * 65 + n] = Wo[(size_t)(n0 + n) * 512 + k0 + kk];
                        }
                    } else {
#pragma unroll
                        for (int it = 0; it < 4; it++) {
                            int j = tid + it * 1024;
                            int kk = j >> 6, n = j & 63;
                            Bs[kk * 65 + n] = Wa[(size_t)(k0 + kk) * 512 + (n0 - 64) + n];
                        }
                    }
                    __syncthreads();
#pragma unroll
                    for (int kk = 0; kk < 64; kk++)
                        acc += As[kk * 17 + om] * Bs[kk * 65 + on];
                }
                int mg = m0 + om;
                if (nt == 0) ob[mg * 64 + on] = acc;
                else         qpre[(size_t)mg * 512 + (n0 - 64) + on] = acc;
            }
        }
        __threadfence();
        grid.sync();
    }

    // final step's dout (t = 62)
    if (tid < 64) {
        const int b = blk, l = tid;
        float v = ob[b * 64 + l] + bo[l];
        dout[(size_t)b * (OO * NSTEP) + l * NSTEP + (NSTEP - 1)] = v;
    }
}

// ---------------------------------------------------------------------------
extern "C" void kernel_launch(void* const* d_in, const int* in_sizes, int n_in,
                              void* d_out, int out_size, void* d_ws, size_t ws_size,
                              hipStream_t stream)
{
    const float* sos  = (const float*)d_in[0];
    const float* h0   = (const float*)d_in[1];
    const float* enc  = (const float*)d_in[2];
    const float* Wa   = (const float*)d_in[3];
    const float* ba   = (const float*)d_in[4];
    const float* vvec = (const float*)d_in[5];
    const float* W_ih = (const float*)d_in[6];
    const float* b_ih = (const float*)d_in[7];
    const float* W_hh = (const float*)d_in[8];
    const float* b_hh = (const float*)d_in[9];
    const float* Wo   = (const float*)d_in[10];
    const float* bo   = (const float*)d_in[11];
    float* out = (float*)d_out;

    // Workspace: exactly 34,111,488 floats (136.4 MB) — the known-good budget.
    float* ws = (float*)d_ws;
    float* EW   = ws; ws += (size_t)SS * BB * HH;   // 33,554,432  [b][s][h]
    float* qpre = ws; ws += BB * HH;                // pre-bias q
    float* ctx  = ws; ws += BB * HH;
    float* hb0  = ws; ws += BB * HH;                // h (post-tanh), buf 0
    float* hb1  = ws; ws += BB * HH;                // h (post-tanh), buf 1
    float* xb   = ws; ws += BB * OO;
    float* ob   = ws; ws += BB * OO;                // pre-bias out

    // ---- Precompute ----
    k_ew_gemm<<<dim3(512, 4), 256, 0, stream>>>(enc, Wa + 512 * 512, EW);
    k_qinit<<<dim3(16, 8), 256, 0, stream>>>(h0, Wa, qpre);

    // ---- Persistent cooperative decode loop (63 steps, 3 phases/step) ----
    void* args[] = {
        (void*)&EW, (void*)&enc, (void*)&qpre, (void*)&ba, (void*)&vvec,
        (void*)&ctx, (void*)&h0, (void*)&sos, (void*)&xb, (void*)&hb0,
        (void*)&hb1, (void*)&W_ih, (void*)&W_hh, (void*)&b_ih, (void*)&b_hh,
        (void*)&Wo, (void*)&Wa, (void*)&bo, (void*)&ob, (void*)&out
    };
    hipLaunchCooperativeKernel((void*)k_loop, dim3(256), dim3(1024),
                               args, 0, stream);
}

// Round 5
// 7411.300 us; speedup vs baseline: 3.9194x; 3.9194x over previous
//
#include <hip/hip_runtime.h>
#include <math.h>

// Problem constants
#define SS 256   // encoder seq len
#define BB 256   // batch
#define HH 512   // hidden
#define OO 64    // output dim
#define NSTEP 63 // only outs[:63] are used

// ---------------------------------------------------------------------------
// K0: EW = enc @ Wa_bot  (M=65536, K=512, N=512), fp32, 128x128 tile.
// Output relayout: row m = s*256+b  ->  EW[b][s][h]  (contiguous per batch b)
// Launched as 8 M-slices (bm0 = slice*8192) so no single dispatch dominates
// the profile; traffic-neutral vs one launch.
// ---------------------------------------------------------------------------
__global__ __launch_bounds__(256) void k_ew_gemm(const float* __restrict__ A,
                                                 const float* __restrict__ Bm,
                                                 float* __restrict__ C,
                                                 int bm0)
{
    __shared__ float As[8][132];
    __shared__ float Bs[8][132];
    const int tid = threadIdx.x;
    const int bm = bm0 + blockIdx.x * 128;
    const int bn = blockIdx.y * 128;
    const int tx = tid & 15;
    const int ty = tid >> 4;
    const int a_row = tid >> 1;
    const int a_k4 = (tid & 1) * 4;
    const int b_row = tid >> 5;
    const int b_n4 = (tid & 31) * 4;

    float acc[8][8];
#pragma unroll
    for (int i = 0; i < 8; i++)
#pragma unroll
        for (int j = 0; j < 8; j++) acc[i][j] = 0.f;

    for (int kt = 0; kt < 512; kt += 8) {
        float4 av = *(const float4*)(A + (size_t)(bm + a_row) * 512 + kt + a_k4);
        As[a_k4 + 0][a_row] = av.x;
        As[a_k4 + 1][a_row] = av.y;
        As[a_k4 + 2][a_row] = av.z;
        As[a_k4 + 3][a_row] = av.w;
        *(float4*)(&Bs[b_row][b_n4]) = *(const float4*)(Bm + (size_t)(kt + b_row) * 512 + bn + b_n4);
        __syncthreads();
#pragma unroll
        for (int kk = 0; kk < 8; kk++) {
            float av8[8], bv8[8];
            *(float4*)&av8[0] = *(const float4*)&As[kk][ty * 4];
            *(float4*)&av8[4] = *(const float4*)&As[kk][64 + ty * 4];
            *(float4*)&bv8[0] = *(const float4*)&Bs[kk][tx * 4];
            *(float4*)&bv8[4] = *(const float4*)&Bs[kk][64 + tx * 4];
#pragma unroll
            for (int i = 0; i < 8; i++)
#pragma unroll
                for (int j = 0; j < 8; j++) acc[i][j] += av8[i] * bv8[j];
        }
        __syncthreads();
    }
#pragma unroll
    for (int i = 0; i < 8; i++) {
        int m = bm + ((i < 4) ? (ty * 4 + i) : (64 + ty * 4 + i - 4));
        int mrow = (m & 255) * 256 + (m >> 8);   // [b][s] relayout
        float4 o0 = make_float4(acc[i][0], acc[i][1], acc[i][2], acc[i][3]);
        float4 o1 = make_float4(acc[i][4], acc[i][5], acc[i][6], acc[i][7]);
        *(float4*)(C + (size_t)mrow * 512 + bn + tx * 4) = o0;
        *(float4*)(C + (size_t)mrow * 512 + bn + 64 + tx * 4) = o1;
    }
}

// ---------------------------------------------------------------------------
// q init: qpre = h0 @ Wa_top   (no bias; ba deferred to k_attn)
// ---------------------------------------------------------------------------
__global__ __launch_bounds__(256) void k_qinit(const float* __restrict__ A,
                                               const float* __restrict__ Wa,
                                               float* __restrict__ qpre)
{
    __shared__ float As[32][33];
    __shared__ float Bs[32][33];
    const int tid = threadIdx.x;
    const int bn = blockIdx.x * 32;
    const int bm = blockIdx.y * 32;
    const int tx = tid & 15;
    const int ty = tid >> 4;
    const int l_row = tid >> 3;
    const int l_c4 = (tid & 7) * 4;

    float acc00 = 0.f, acc01 = 0.f, acc10 = 0.f, acc11 = 0.f;
    for (int kt = 0; kt < 512; kt += 32) {
#pragma unroll
        for (int i = 0; i < 4; i++)
            As[l_c4 + i][l_row] = A[(size_t)(bm + l_row) * 512 + kt + l_c4 + i];
#pragma unroll
        for (int i = 0; i < 4; i++)
            Bs[l_row][l_c4 + i] = Wa[(size_t)(kt + l_row) * 512 + bn + l_c4 + i];
        __syncthreads();
#pragma unroll
        for (int kk = 0; kk < 32; kk++) {
            float a0 = As[kk][ty * 2], a1 = As[kk][ty * 2 + 1];
            float b0 = Bs[kk][tx * 2], b1 = Bs[kk][tx * 2 + 1];
            acc00 += a0 * b0; acc01 += a0 * b1;
            acc10 += a1 * b0; acc11 += a1 * b1;
        }
        __syncthreads();
    }
    qpre[(size_t)(bm + ty * 2) * 512 + bn + tx * 2]     = acc00;
    qpre[(size_t)(bm + ty * 2) * 512 + bn + tx * 2 + 1] = acc01;
    qpre[(size_t)(bm + ty * 2 + 1) * 512 + bn + tx * 2]     = acc10;
    qpre[(size_t)(bm + ty * 2 + 1) * 512 + bn + tx * 2 + 1] = acc11;
}

// ---------------------------------------------------------------------------
// k_attn: per batch b.
//  - wave 0 (t>0): argmax of prev step's ob[b]+bo -> xb one-hot, dout[t-1].
//  - zero hpre_out slice (this step's k_h atomics). ob zeroed in k_h.
//  - scores: tanh(EW[b][s]+q[b])·v; softmax over s; context from enc.
// 1024 threads = 16 waves; wave w owns s in [w*16,w*16+16); lane l owns
// h = l*8..l*8+7. 2-way s-unroll (round-2-proven body). fp32 + libm tanhf.
// ---------------------------------------------------------------------------
__global__ __launch_bounds__(1024) void k_attn(const float* __restrict__ EW,
                                               const float* __restrict__ enc,
                                               const float* __restrict__ qpre,
                                               const float* __restrict__ ba,
                                               const float* __restrict__ vvec,
                                               float* __restrict__ ctx,
                                               float* __restrict__ hpre_out,
                                               const float* __restrict__ ob,
                                               const float* __restrict__ bo,
                                               float* __restrict__ dout,
                                               float* __restrict__ xb,
                                               int t)
{
    __shared__ float qs[512];
    __shared__ float vs[512];
    __shared__ float sc[256];
    __shared__ float red[16];
    __shared__ float ctxp[16][512];
    const int b = blockIdx.x;
    const int tid = threadIdx.x;

    // prev-step argmax + dout write (ob complete from k_outq(t-1); ob is NOT
    // zeroed here — that lives in k_h — so no cross-block race).
    if (t > 0 && tid < 64) {
        const int l = tid;
        float v = ob[b * 64 + l] + bo[l];
        dout[(size_t)b * (OO * NSTEP) + l * NSTEP + (t - 1)] = v;
        int bi = l;
        float bv = v;
#pragma unroll
        for (int off = 1; off < 64; off <<= 1) {
            float ov = __shfl_xor(bv, off);
            int oi = __shfl_xor(bi, off);
            if (ov > bv || (ov == bv && oi < bi)) { bv = ov; bi = oi; }
        }
        xb[b * 64 + l] = (l == bi) ? 1.0f : 0.0f;
    }

    // zero this step's hpre accumulator slice (hpre only)
    if (tid < 576) {
        int idx = b * 576 + tid;
        if (idx < 131072) hpre_out[idx] = 0.f;
    }

    if (tid < 512) {
        qs[tid] = qpre[b * 512 + tid] + ba[tid];
        vs[tid] = vvec[tid];
    }
    __syncthreads();

    const int w = tid >> 6;    // 0..15
    const int l = tid & 63;

    float qv[8], vv[8];
    *(float4*)&qv[0] = *(const float4*)&qs[l * 8];
    *(float4*)&qv[4] = *(const float4*)&qs[l * 8 + 4];
    *(float4*)&vv[0] = *(const float4*)&vs[l * 8];
    *(float4*)&vv[4] = *(const float4*)&vs[l * 8 + 4];

    // ---- phase 1: scores (wave w: s = w*16 .. w*16+15, 2-way unrolled) ----
    {
        const float4* pe = (const float4*)(EW + ((size_t)b * 256 + w * 16) * 512);
        for (int i = 0; i < 16; i += 2) {
            float4 e00 = pe[(size_t)i * 128 + 2 * l];
            float4 e01 = pe[(size_t)i * 128 + 2 * l + 1];
            float4 e10 = pe[(size_t)(i + 1) * 128 + 2 * l];
            float4 e11 = pe[(size_t)(i + 1) * 128 + 2 * l + 1];
            float a0, a1;
            a0  = vv[0] * tanhf(e00.x + qv[0]);
            a0 += vv[1] * tanhf(e00.y + qv[1]);
            a0 += vv[2] * tanhf(e00.z + qv[2]);
            a0 += vv[3] * tanhf(e00.w + qv[3]);
            a0 += vv[4] * tanhf(e01.x + qv[4]);
            a0 += vv[5] * tanhf(e01.y + qv[5]);
            a0 += vv[6] * tanhf(e01.z + qv[6]);
            a0 += vv[7] * tanhf(e01.w + qv[7]);
            a1  = vv[0] * tanhf(e10.x + qv[0]);
            a1 += vv[1] * tanhf(e10.y + qv[1]);
            a1 += vv[2] * tanhf(e10.z + qv[2]);
            a1 += vv[3] * tanhf(e10.w + qv[3]);
            a1 += vv[4] * tanhf(e11.x + qv[4]);
            a1 += vv[5] * tanhf(e11.y + qv[5]);
            a1 += vv[6] * tanhf(e11.z + qv[6]);
            a1 += vv[7] * tanhf(e11.w + qv[7]);
#pragma unroll
            for (int off = 32; off; off >>= 1) {
                a0 += __shfl_down(a0, off);
                a1 += __shfl_down(a1, off);
            }
            if (l == 0) {
                sc[w * 16 + i]     = a0;
                sc[w * 16 + i + 1] = a1;
            }
        }
    }
    __syncthreads();

    // ---- softmax over s (waves 0-3) ----
    if (tid < 256) {
        float m = sc[tid];
#pragma unroll
        for (int off = 32; off; off >>= 1) m = fmaxf(m, __shfl_down(m, off));
        if ((tid & 63) == 0) red[tid >> 6] = m;
    }
    __syncthreads();
    if (tid < 256) {
        float mx = fmaxf(fmaxf(red[0], red[1]), fmaxf(red[2], red[3]));
        float e = expf(sc[tid] - mx);
        sc[tid] = e;
        float ssum = e;
#pragma unroll
        for (int off = 32; off; off >>= 1) ssum += __shfl_down(ssum, off);
        if ((tid & 63) == 0) red[8 + (tid >> 6)] = ssum;
    }
    __syncthreads();
    const float inv = 1.0f / (red[8] + red[9] + red[10] + red[11]);

    // ---- phase 2: partial context (wave w: s = w*16 .. w*16+15) ----
    {
        float c[8];
#pragma unroll
        for (int j = 0; j < 8; j++) c[j] = 0.f;
        for (int i = 0; i < 16; i += 2) {
            int s0 = w * 16 + i;
            int s1 = s0 + 1;
            float w0 = sc[s0];
            float w1 = sc[s1];
            const float4* p0 = (const float4*)(enc + ((size_t)s0 * 256 + b) * 512);
            const float4* p1 = (const float4*)(enc + ((size_t)s1 * 256 + b) * 512);
            float4 e00 = p0[2 * l];
            float4 e01 = p0[2 * l + 1];
            float4 e10 = p1[2 * l];
            float4 e11 = p1[2 * l + 1];
            c[0] += w0 * e00.x; c[1] += w0 * e00.y;
            c[2] += w0 * e00.z; c[3] += w0 * e00.w;
            c[4] += w0 * e01.x; c[5] += w0 * e01.y;
            c[6] += w0 * e01.z; c[7] += w0 * e01.w;
            c[0] += w1 * e10.x; c[1] += w1 * e10.y;
            c[2] += w1 * e10.z; c[3] += w1 * e10.w;
            c[4] += w1 * e11.x; c[5] += w1 * e11.y;
            c[6] += w1 * e11.z; c[7] += w1 * e11.w;
        }
        float4 c0 = make_float4(c[0], c[1], c[2], c[3]);
        float4 c1 = make_float4(c[4], c[5], c[6], c[7]);
        *(float4*)&ctxp[w][l * 8]     = c0;
        *(float4*)&ctxp[w][l * 8 + 4] = c1;
    }
    __syncthreads();
    if (tid < 512) {
        float r = 0.f;
#pragma unroll
        for (int g = 0; g < 16; g++) r += ctxp[g][tid];
        ctx[b * 512 + tid] = r * inv;
    }
}

// ---------------------------------------------------------------------------
// k_h: hpre_out += [x | ctx | h_prev] @ [W_ih | W_hh]^T   (k-split atomic)
// grid (8 nblk, 8 mblk, 8 kchunk), tile 32m x 64n, BK=8, K-chunk=136.
// Also zeroes qpre (all blocks) and ob (z==7 blocks) for this step's atomics.
// ---------------------------------------------------------------------------
__global__ __launch_bounds__(256) void k_h(
    const float* __restrict__ xin, const float* __restrict__ ctx,
    const float* __restrict__ hpre_in, const float* __restrict__ h0,
    int t0,
    const float* __restrict__ W_ih, const float* __restrict__ W_hh,
    const float* __restrict__ b_ih, const float* __restrict__ b_hh,
    float* __restrict__ hpre_out, float* __restrict__ qpre,
    float* __restrict__ ob)
{
    __shared__ float As[8][34];
    __shared__ float Bs[8][68];
    const int tid = threadIdx.x;
    const int bn = blockIdx.x * 64;
    const int bm = blockIdx.y * 32;
    const int k0 = blockIdx.z * 136;

    // zero qpre: 512 blocks x 256 threads = 131072
    {
        int lin = ((blockIdx.z * 8 + blockIdx.y) * 8 + blockIdx.x) * 256 + tid;
        qpre[lin] = 0.f;
    }
    // zero ob: z==7 blocks: 64 x 256 = 16384
    if (blockIdx.z == 7) {
        int lin = (blockIdx.y * 8 + blockIdx.x) * 256 + tid;
        ob[lin] = 0.f;
    }

    const int tx = tid & 15;
    const int ty = tid >> 4;
    const int sa_k = tid & 7;
    const int sa_m = tid >> 3;
    const int sb_n = tid >> 2;
    const int sb_k = (tid & 3) * 2;

    float acc[2][4];
#pragma unroll
    for (int i = 0; i < 2; i++)
#pragma unroll
        for (int j = 0; j < 4; j++) acc[i][j] = 0.f;

    for (int kt = 0; kt < 17; kt++) {
        const int kb = k0 + kt * 8;
        {
            int m = bm + sa_m;
            int k = kb + sa_k;
            float v;
            if (k < 64) v = xin[m * 64 + k];
            else if (k < 576) v = ctx[m * 512 + (k - 64)];
            else {
                int kh = k - 576;
                v = t0 ? h0[m * 512 + kh]
                       : tanhf(hpre_in[m * 512 + kh] + b_ih[kh] + b_hh[kh]);
            }
            As[sa_k][sa_m] = v;
        }
        {
            int n = bn + sb_n;
#pragma unroll
            for (int i = 0; i < 2; i++) {
                int k = kb + sb_k + i;
                float v = (k < 576) ? W_ih[(size_t)n * 576 + k]
                                    : W_hh[(size_t)n * 512 + (k - 576)];
                Bs[sb_k + i][sb_n] = v;
            }
        }
        __syncthreads();
#pragma unroll
        for (int kk = 0; kk < 8; kk++) {
            float a0 = As[kk][ty * 2], a1 = As[kk][ty * 2 + 1];
            float b0 = Bs[kk][tx * 4], b1 = Bs[kk][tx * 4 + 1];
            float b2 = Bs[kk][tx * 4 + 2], b3 = Bs[kk][tx * 4 + 3];
            acc[0][0] += a0 * b0; acc[0][1] += a0 * b1;
            acc[0][2] += a0 * b2; acc[0][3] += a0 * b3;
            acc[1][0] += a1 * b0; acc[1][1] += a1 * b1;
            acc[1][2] += a1 * b2; acc[1][3] += a1 * b3;
        }
        __syncthreads();
    }
#pragma unroll
    for (int i = 0; i < 2; i++) {
        int m = bm + ty * 2 + i;
#pragma unroll
        for (int j = 0; j < 4; j++) {
            atomicAdd(&hpre_out[(size_t)m * 512 + bn + tx * 4 + j], acc[i][j]);
        }
    }
}

// ---------------------------------------------------------------------------
// k_outq: combined N=576: n<64: ob += h @ Wo^T ; n>=64: qpre += h @ Wa_top
// ---------------------------------------------------------------------------
__global__ __launch_bounds__(256) void k_outq(
    const float* __restrict__ hpre_cur,
    const float* __restrict__ b_ih, const float* __restrict__ b_hh,
    const float* __restrict__ Wo, const float* __restrict__ Wa,
    float* __restrict__ ob, float* __restrict__ qpre)
{
    __shared__ float As[8][34];
    __shared__ float Bs[8][68];
    const int tid = threadIdx.x;
    const int bn = blockIdx.x * 64;
    const int bm = blockIdx.y * 32;
    const int k0 = blockIdx.z * 128;
    const bool is_out = (bn < 64);

    const int tx = tid & 15;
    const int ty = tid >> 4;
    const int sa_k = tid & 7;
    const int sa_m = tid >> 3;
    const int sb_n = tid >> 2;
    const int sb_k = (tid & 3) * 2;
    const int qa_k = tid >> 5;
    const int qa_n = (tid & 31) * 2;

    float acc[2][4];
#pragma unroll
    for (int i = 0; i < 2; i++)
#pragma unroll
        for (int j = 0; j < 4; j++) acc[i][j] = 0.f;

    for (int kt = 0; kt < 16; kt++) {
        const int kb = k0 + kt * 8;
        {
            int m = bm + sa_m;
            int k = kb + sa_k;
            As[sa_k][sa_m] = tanhf(hpre_cur[(size_t)m * 512 + k] + b_ih[k] + b_hh[k]);
        }
        if (is_out) {
            int n = bn + sb_n;
#pragma unroll
            for (int i = 0; i < 2; i++) {
                int k = kb + sb_k + i;
                Bs[sb_k + i][sb_n] = Wo[(size_t)n * 512 + k];
            }
        } else {
            int k = kb + qa_k;
            int n = bn - 64 + qa_n;
#pragma unroll
            for (int i = 0; i < 2; i++)
                Bs[qa_k][qa_n + i] = Wa[(size_t)k * 512 + n + i];
        }
        __syncthreads();
#pragma unroll
        for (int kk = 0; kk < 8; kk++) {
            float a0 = As[kk][ty * 2], a1 = As[kk][ty * 2 + 1];
            float b0 = Bs[kk][tx * 4], b1 = Bs[kk][tx * 4 + 1];
            float b2 = Bs[kk][tx * 4 + 2], b3 = Bs[kk][tx * 4 + 3];
            acc[0][0] += a0 * b0; acc[0][1] += a0 * b1;
            acc[0][2] += a0 * b2; acc[0][3] += a0 * b3;
            acc[1][0] += a1 * b0; acc[1][1] += a1 * b1;
            acc[1][2] += a1 * b2; acc[1][3] += a1 * b3;
        }
        __syncthreads();
    }
#pragma unroll
    for (int i = 0; i < 2; i++) {
        int m = bm + ty * 2 + i;
#pragma unroll
        for (int j = 0; j < 4; j++) {
            int n = bn + tx * 4 + j;
            if (is_out) atomicAdd(&ob[m * 64 + n], acc[i][j]);
            else        atomicAdd(&qpre[(size_t)m * 512 + (n - 64)], acc[i][j]);
        }
    }
}

// ---------------------------------------------------------------------------
// k_argmax: final-step dout write (t=62). out = ob + bo; dout[b][n][t].
// ---------------------------------------------------------------------------
__global__ __launch_bounds__(256) void k_argmax(const float* __restrict__ ob,
                                                const float* __restrict__ bo,
                                                float* __restrict__ dout, int t,
                                                float* __restrict__ x)
{
    const int b = blockIdx.x * 4 + (threadIdx.x >> 6);
    const int l = threadIdx.x & 63;
    float v = ob[b * 64 + l] + bo[l];
    dout[(size_t)b * (OO * NSTEP) + l * NSTEP + t] = v;
    int bi = l;
    float bv = v;
#pragma unroll
    for (int off = 1; off < 64; off <<= 1) {
        float ov = __shfl_xor(bv, off);
        int oi = __shfl_xor(bi, off);
        if (ov > bv || (ov == bv && oi < bi)) { bv = ov; bi = oi; }
    }
    x[b * 64 + l] = (l == bi) ? 1.0f : 0.0f;
}

// ---------------------------------------------------------------------------
extern "C" void kernel_launch(void* const* d_in, const int* in_sizes, int n_in,
                              void* d_out, int out_size, void* d_ws, size_t ws_size,
                              hipStream_t stream)
{
    const float* sos  = (const float*)d_in[0];
    const float* h0   = (const float*)d_in[1];
    const float* enc  = (const float*)d_in[2];
    const float* Wa   = (const float*)d_in[3];
    const float* ba   = (const float*)d_in[4];
    const float* vvec = (const float*)d_in[5];
    const float* W_ih = (const float*)d_in[6];
    const float* b_ih = (const float*)d_in[7];
    const float* W_hh = (const float*)d_in[8];
    const float* b_hh = (const float*)d_in[9];
    const float* Wo   = (const float*)d_in[10];
    const float* bo   = (const float*)d_in[11];
    float* out = (float*)d_out;

    // Workspace: exactly 34,111,488 floats (136.4 MB) — the known-good budget.
    float* ws = (float*)d_ws;
    float* EW    = ws; ws += (size_t)SS * BB * HH;   // 33,554,432  [b][s][h]
    float* qpre  = ws; ws += BB * HH;                // pre-bias q
    float* ctx   = ws; ws += BB * HH;
    float* hpre0 = ws; ws += BB * HH;                // pre-activation h
    float* hpre1 = ws; ws += BB * HH;
    float* xb    = ws; ws += BB * OO;
    float* ob    = ws; ws += BB * OO;                // pre-bias out

    // ---- Precompute (8 M-slices; traffic-neutral split for profiling) ----
    for (int s8 = 0; s8 < 8; s8++)
        k_ew_gemm<<<dim3(64, 4), 256, 0, stream>>>(enc, Wa + 512 * 512, EW,
                                                   s8 * 8192);
    k_qinit<<<dim3(16, 8), 256, 0, stream>>>(h0, Wa, qpre);

    // ---- 63 decode steps (3 kernels/step; argmax folded into k_attn) ----
    for (int t = 0; t < NSTEP; t++) {
        float* hpre_out = (t & 1) ? hpre1 : hpre0;
        float* hpre_in  = (t & 1) ? hpre0 : hpre1;   // valid for t>=1
        const float* xin = (t == 0) ? sos : xb;

        // prev-step argmax/dout + attention (+ zero hpre_out)
        k_attn<<<256, 1024, 0, stream>>>(EW, enc, qpre, ba, vvec, ctx,
                                         hpre_out, ob, bo, out, xb, t);

        // hpre_out += [x|ctx|h_prev] @ Wcat^T   (+ zero qpre, ob)
        k_h<<<dim3(8, 8, 8), 256, 0, stream>>>(xin, ctx, hpre_in, h0, (t == 0) ? 1 : 0,
                                               W_ih, W_hh, b_ih, b_hh,
                                               hpre_out, qpre, ob);

        // ob += h @ Wo^T ; qpre += h @ Wa_top
        k_outq<<<dim3(9, 8, 4), 256, 0, stream>>>(hpre_out, b_ih, b_hh,
                                                  Wo, Wa, ob, qpre);
    }

    // final step's dout (t = 62)
    k_argmax<<<64, 256, 0, stream>>>(ob, bo, out, NSTEP - 1, xb);
}

// Round 6
// 6719.379 us; speedup vs baseline: 4.3230x; 1.1030x over previous
//
#include <hip/hip_runtime.h>
#include <math.h>

// Problem constants
#define SS 256   // encoder seq len
#define BB 256   // batch
#define HH 512   // hidden
#define OO 64    // output dim
#define NSTEP 63 // only outs[:63] are used

// Fast tanh for the SCORE path only: tanh(x) = 1 - 2/(e^{2x}+1),
// e^{2x} = 2^{2x*log2 e}. abs err ~2e-7 — below the fp32 GEMM noise already
// in EW. The recurrence path (k_h/k_outq) keeps libm tanhf.
__device__ __forceinline__ float fast_tanh(float x) {
    float e = __builtin_amdgcn_exp2f(x * 2.885390081777927f);
    return 1.f - 2.f * __builtin_amdgcn_rcpf(e + 1.f);
}

// ---------------------------------------------------------------------------
// K0: EW = enc @ Wa_bot  (M=65536, K=512, N=512), fp32, 128x128 tile.
// Output relayout: row m = s*256+b  ->  EW[b][s][h]  (contiguous per batch b)
// Single dispatch (8-way M-split measured 2x slower: 8x105 vs 402 us).
// ---------------------------------------------------------------------------
__global__ __launch_bounds__(256) void k_ew_gemm(const float* __restrict__ A,
                                                 const float* __restrict__ Bm,
                                                 float* __restrict__ C)
{
    __shared__ float As[8][132];
    __shared__ float Bs[8][132];
    const int tid = threadIdx.x;
    const int bm = blockIdx.x * 128;
    const int bn = blockIdx.y * 128;
    const int tx = tid & 15;
    const int ty = tid >> 4;
    const int a_row = tid >> 1;
    const int a_k4 = (tid & 1) * 4;
    const int b_row = tid >> 5;
    const int b_n4 = (tid & 31) * 4;

    float acc[8][8];
#pragma unroll
    for (int i = 0; i < 8; i++)
#pragma unroll
        for (int j = 0; j < 8; j++) acc[i][j] = 0.f;

    for (int kt = 0; kt < 512; kt += 8) {
        float4 av = *(const float4*)(A + (size_t)(bm + a_row) * 512 + kt + a_k4);
        As[a_k4 + 0][a_row] = av.x;
        As[a_k4 + 1][a_row] = av.y;
        As[a_k4 + 2][a_row] = av.z;
        As[a_k4 + 3][a_row] = av.w;
        *(float4*)(&Bs[b_row][b_n4]) = *(const float4*)(Bm + (size_t)(kt + b_row) * 512 + bn + b_n4);
        __syncthreads();
#pragma unroll
        for (int kk = 0; kk < 8; kk++) {
            float av8[8], bv8[8];
            *(float4*)&av8[0] = *(const float4*)&As[kk][ty * 4];
            *(float4*)&av8[4] = *(const float4*)&As[kk][64 + ty * 4];
            *(float4*)&bv8[0] = *(const float4*)&Bs[kk][tx * 4];
            *(float4*)&bv8[4] = *(const float4*)&Bs[kk][64 + tx * 4];
#pragma unroll
            for (int i = 0; i < 8; i++)
#pragma unroll
                for (int j = 0; j < 8; j++) acc[i][j] += av8[i] * bv8[j];
        }
        __syncthreads();
    }
#pragma unroll
    for (int i = 0; i < 8; i++) {
        int m = bm + ((i < 4) ? (ty * 4 + i) : (64 + ty * 4 + i - 4));
        int mrow = (m & 255) * 256 + (m >> 8);   // [b][s] relayout
        float4 o0 = make_float4(acc[i][0], acc[i][1], acc[i][2], acc[i][3]);
        float4 o1 = make_float4(acc[i][4], acc[i][5], acc[i][6], acc[i][7]);
        *(float4*)(C + (size_t)mrow * 512 + bn + tx * 4) = o0;
        *(float4*)(C + (size_t)mrow * 512 + bn + 64 + tx * 4) = o1;
    }
}

// ---------------------------------------------------------------------------
// q init: qpre = h0 @ Wa_top   (no bias; ba deferred to k_attn)
// ---------------------------------------------------------------------------
__global__ __launch_bounds__(256) void k_qinit(const float* __restrict__ A,
                                               const float* __restrict__ Wa,
                                               float* __restrict__ qpre)
{
    __shared__ float As[32][33];
    __shared__ float Bs[32][33];
    const int tid = threadIdx.x;
    const int bn = blockIdx.x * 32;
    const int bm = blockIdx.y * 32;
    const int tx = tid & 15;
    const int ty = tid >> 4;
    const int l_row = tid >> 3;
    const int l_c4 = (tid & 7) * 4;

    float acc00 = 0.f, acc01 = 0.f, acc10 = 0.f, acc11 = 0.f;
    for (int kt = 0; kt < 512; kt += 32) {
#pragma unroll
        for (int i = 0; i < 4; i++)
            As[l_c4 + i][l_row] = A[(size_t)(bm + l_row) * 512 + kt + l_c4 + i];
#pragma unroll
        for (int i = 0; i < 4; i++)
            Bs[l_row][l_c4 + i] = Wa[(size_t)(kt + l_row) * 512 + bn + l_c4 + i];
        __syncthreads();
#pragma unroll
        for (int kk = 0; kk < 32; kk++) {
            float a0 = As[kk][ty * 2], a1 = As[kk][ty * 2 + 1];
            float b0 = Bs[kk][tx * 2], b1 = Bs[kk][tx * 2 + 1];
            acc00 += a0 * b0; acc01 += a0 * b1;
            acc10 += a1 * b0; acc11 += a1 * b1;
        }
        __syncthreads();
    }
    qpre[(size_t)(bm + ty * 2) * 512 + bn + tx * 2]     = acc00;
    qpre[(size_t)(bm + ty * 2) * 512 + bn + tx * 2 + 1] = acc01;
    qpre[(size_t)(bm + ty * 2 + 1) * 512 + bn + tx * 2]     = acc10;
    qpre[(size_t)(bm + ty * 2 + 1) * 512 + bn + tx * 2 + 1] = acc11;
}

// ---------------------------------------------------------------------------
// k_attn: per batch b.
//  - wave 0 (t>0): argmax of prev step's ob[b]+bo -> xb one-hot, dout[t-1].
//  - zero hpre_out slice (this step's k_h atomics). ob zeroed in k_h.
//  - scores: fast_tanh(EW[b][s]+q[b])·v; softmax over s; context from enc.
// 1024 threads = 16 waves; wave w owns s in [w*16,w*16+16); lane l owns
// h = l*8..l*8+7. 2-way s-unroll (round-2-proven body).
// ---------------------------------------------------------------------------
__global__ __launch_bounds__(1024) void k_attn(const float* __restrict__ EW,
                                               const float* __restrict__ enc,
                                               const float* __restrict__ qpre,
                                               const float* __restrict__ ba,
                                               const float* __restrict__ vvec,
                                               float* __restrict__ ctx,
                                               float* __restrict__ hpre_out,
                                               const float* __restrict__ ob,
                                               const float* __restrict__ bo,
                                               float* __restrict__ dout,
                                               float* __restrict__ xb,
                                               int t)
{
    __shared__ float qs[512];
    __shared__ float vs[512];
    __shared__ float sc[256];
    __shared__ float red[16];
    __shared__ float ctxp[16][512];
    const int b = blockIdx.x;
    const int tid = threadIdx.x;

    // prev-step argmax + dout write (ob complete from k_outq(t-1); ob is NOT
    // zeroed here — that lives in k_h — so no cross-block race).
    if (t > 0 && tid < 64) {
        const int l = tid;
        float v = ob[b * 64 + l] + bo[l];
        dout[(size_t)b * (OO * NSTEP) + l * NSTEP + (t - 1)] = v;
        int bi = l;
        float bv = v;
#pragma unroll
        for (int off = 1; off < 64; off <<= 1) {
            float ov = __shfl_xor(bv, off);
            int oi = __shfl_xor(bi, off);
            if (ov > bv || (ov == bv && oi < bi)) { bv = ov; bi = oi; }
        }
        xb[b * 64 + l] = (l == bi) ? 1.0f : 0.0f;
    }

    // zero this step's hpre accumulator slice (hpre only)
    if (tid < 576) {
        int idx = b * 576 + tid;
        if (idx < 131072) hpre_out[idx] = 0.f;
    }

    if (tid < 512) {
        qs[tid] = qpre[b * 512 + tid] + ba[tid];
        vs[tid] = vvec[tid];
    }
    __syncthreads();

    const int w = tid >> 6;    // 0..15
    const int l = tid & 63;

    float qv[8], vv[8];
    *(float4*)&qv[0] = *(const float4*)&qs[l * 8];
    *(float4*)&qv[4] = *(const float4*)&qs[l * 8 + 4];
    *(float4*)&vv[0] = *(const float4*)&vs[l * 8];
    *(float4*)&vv[4] = *(const float4*)&vs[l * 8 + 4];

    // ---- phase 1: scores (wave w: s = w*16 .. w*16+15, 2-way unrolled) ----
    {
        const float4* pe = (const float4*)(EW + ((size_t)b * 256 + w * 16) * 512);
        for (int i = 0; i < 16; i += 2) {
            float4 e00 = pe[(size_t)i * 128 + 2 * l];
            float4 e01 = pe[(size_t)i * 128 + 2 * l + 1];
            float4 e10 = pe[(size_t)(i + 1) * 128 + 2 * l];
            float4 e11 = pe[(size_t)(i + 1) * 128 + 2 * l + 1];
            float a0, a1;
            a0  = vv[0] * fast_tanh(e00.x + qv[0]);
            a0 += vv[1] * fast_tanh(e00.y + qv[1]);
            a0 += vv[2] * fast_tanh(e00.z + qv[2]);
            a0 += vv[3] * fast_tanh(e00.w + qv[3]);
            a0 += vv[4] * fast_tanh(e01.x + qv[4]);
            a0 += vv[5] * fast_tanh(e01.y + qv[5]);
            a0 += vv[6] * fast_tanh(e01.z + qv[6]);
            a0 += vv[7] * fast_tanh(e01.w + qv[7]);
            a1  = vv[0] * fast_tanh(e10.x + qv[0]);
            a1 += vv[1] * fast_tanh(e10.y + qv[1]);
            a1 += vv[2] * fast_tanh(e10.z + qv[2]);
            a1 += vv[3] * fast_tanh(e10.w + qv[3]);
            a1 += vv[4] * fast_tanh(e11.x + qv[4]);
            a1 += vv[5] * fast_tanh(e11.y + qv[5]);
            a1 += vv[6] * fast_tanh(e11.z + qv[6]);
            a1 += vv[7] * fast_tanh(e11.w + qv[7]);
#pragma unroll
            for (int off = 32; off; off >>= 1) {
                a0 += __shfl_down(a0, off);
                a1 += __shfl_down(a1, off);
            }
            if (l == 0) {
                sc[w * 16 + i]     = a0;
                sc[w * 16 + i + 1] = a1;
            }
        }
    }
    __syncthreads();

    // ---- softmax over s (waves 0-3) ----
    if (tid < 256) {
        float m = sc[tid];
#pragma unroll
        for (int off = 32; off; off >>= 1) m = fmaxf(m, __shfl_down(m, off));
        if ((tid & 63) == 0) red[tid >> 6] = m;
    }
    __syncthreads();
    if (tid < 256) {
        float mx = fmaxf(fmaxf(red[0], red[1]), fmaxf(red[2], red[3]));
        float e = expf(sc[tid] - mx);
        sc[tid] = e;
        float ssum = e;
#pragma unroll
        for (int off = 32; off; off >>= 1) ssum += __shfl_down(ssum, off);
        if ((tid & 63) == 0) red[8 + (tid >> 6)] = ssum;
    }
    __syncthreads();
    const float inv = 1.0f / (red[8] + red[9] + red[10] + red[11]);

    // ---- phase 2: partial context (wave w: s = w*16 .. w*16+15) ----
    {
        float c[8];
#pragma unroll
        for (int j = 0; j < 8; j++) c[j] = 0.f;
        for (int i = 0; i < 16; i += 2) {
            int s0 = w * 16 + i;
            int s1 = s0 + 1;
            float w0 = sc[s0];
            float w1 = sc[s1];
            const float4* p0 = (const float4*)(enc + ((size_t)s0 * 256 + b) * 512);
            const float4* p1 = (const float4*)(enc + ((size_t)s1 * 256 + b) * 512);
            float4 e00 = p0[2 * l];
            float4 e01 = p0[2 * l + 1];
            float4 e10 = p1[2 * l];
            float4 e11 = p1[2 * l + 1];
            c[0] += w0 * e00.x; c[1] += w0 * e00.y;
            c[2] += w0 * e00.z; c[3] += w0 * e00.w;
            c[4] += w0 * e01.x; c[5] += w0 * e01.y;
            c[6] += w0 * e01.z; c[7] += w0 * e01.w;
            c[0] += w1 * e10.x; c[1] += w1 * e10.y;
            c[2] += w1 * e10.z; c[3] += w1 * e10.w;
            c[4] += w1 * e11.x; c[5] += w1 * e11.y;
            c[6] += w1 * e11.z; c[7] += w1 * e11.w;
        }
        float4 c0 = make_float4(c[0], c[1], c[2], c[3]);
        float4 c1 = make_float4(c[4], c[5], c[6], c[7]);
        *(float4*)&ctxp[w][l * 8]     = c0;
        *(float4*)&ctxp[w][l * 8 + 4] = c1;
    }
    __syncthreads();
    if (tid < 512) {
        float r = 0.f;
#pragma unroll
        for (int g = 0; g < 16; g++) r += ctxp[g][tid];
        ctx[b * 512 + tid] = r * inv;
    }
}

// ---------------------------------------------------------------------------
// k_h: hpre_out += [x | ctx | h_prev] @ [W_ih | W_hh]^T   (k-split atomic)
// grid (8 nblk, 8 mblk, 8 kchunk), tile 32m x 64n, BK=8, K-chunk=136.
// Also zeroes qpre (all blocks) and ob (z==7 blocks) for this step's atomics.
// Recurrence path keeps libm tanhf (no new error on the state path).
// ---------------------------------------------------------------------------
__global__ __launch_bounds__(256) void k_h(
    const float* __restrict__ xin, const float* __restrict__ ctx,
    const float* __restrict__ hpre_in, const float* __restrict__ h0,
    int t0,
    const float* __restrict__ W_ih, const float* __restrict__ W_hh,
    const float* __restrict__ b_ih, const float* __restrict__ b_hh,
    float* __restrict__ hpre_out, float* __restrict__ qpre,
    float* __restrict__ ob)
{
    __shared__ float As[8][34];
    __shared__ float Bs[8][68];
    const int tid = threadIdx.x;
    const int bn = blockIdx.x * 64;
    const int bm = blockIdx.y * 32;
    const int k0 = blockIdx.z * 136;

    // zero qpre: 512 blocks x 256 threads = 131072
    {
        int lin = ((blockIdx.z * 8 + blockIdx.y) * 8 + blockIdx.x) * 256 + tid;
        qpre[lin] = 0.f;
    }
    // zero ob: z==7 blocks: 64 x 256 = 16384
    if (blockIdx.z == 7) {
        int lin = (blockIdx.y * 8 + blockIdx.x) * 256 + tid;
        ob[lin] = 0.f;
    }

    const int tx = tid & 15;
    const int ty = tid >> 4;
    const int sa_k = tid & 7;
    const int sa_m = tid >> 3;
    const int sb_n = tid >> 2;
    const int sb_k = (tid & 3) * 2;

    float acc[2][4];
#pragma unroll
    for (int i = 0; i < 2; i++)
#pragma unroll
        for (int j = 0; j < 4; j++) acc[i][j] = 0.f;

    for (int kt = 0; kt < 17; kt++) {
        const int kb = k0 + kt * 8;
        {
            int m = bm + sa_m;
            int k = kb + sa_k;
            float v;
            if (k < 64) v = xin[m * 64 + k];
            else if (k < 576) v = ctx[m * 512 + (k - 64)];
            else {
                int kh = k - 576;
                v = t0 ? h0[m * 512 + kh]
                       : tanhf(hpre_in[m * 512 + kh] + b_ih[kh] + b_hh[kh]);
            }
            As[sa_k][sa_m] = v;
        }
        {
            int n = bn + sb_n;
#pragma unroll
            for (int i = 0; i < 2; i++) {
                int k = kb + sb_k + i;
                float v = (k < 576) ? W_ih[(size_t)n * 576 + k]
                                    : W_hh[(size_t)n * 512 + (k - 576)];
                Bs[sb_k + i][sb_n] = v;
            }
        }
        __syncthreads();
#pragma unroll
        for (int kk = 0; kk < 8; kk++) {
            float a0 = As[kk][ty * 2], a1 = As[kk][ty * 2 + 1];
            float b0 = Bs[kk][tx * 4], b1 = Bs[kk][tx * 4 + 1];
            float b2 = Bs[kk][tx * 4 + 2], b3 = Bs[kk][tx * 4 + 3];
            acc[0][0] += a0 * b0; acc[0][1] += a0 * b1;
            acc[0][2] += a0 * b2; acc[0][3] += a0 * b3;
            acc[1][0] += a1 * b0; acc[1][1] += a1 * b1;
            acc[1][2] += a1 * b2; acc[1][3] += a1 * b3;
        }
        __syncthreads();
    }
#pragma unroll
    for (int i = 0; i < 2; i++) {
        int m = bm + ty * 2 + i;
#pragma unroll
        for (int j = 0; j < 4; j++) {
            atomicAdd(&hpre_out[(size_t)m * 512 + bn + tx * 4 + j], acc[i][j]);
        }
    }
}

// ---------------------------------------------------------------------------
// k_outq: combined N=576: n<64: ob += h @ Wo^T ; n>=64: qpre += h @ Wa_top
// ---------------------------------------------------------------------------
__global__ __launch_bounds__(256) void k_outq(
    const float* __restrict__ hpre_cur,
    const float* __restrict__ b_ih, const float* __restrict__ b_hh,
    const float* __restrict__ Wo, const float* __restrict__ Wa,
    float* __restrict__ ob, float* __restrict__ qpre)
{
    __shared__ float As[8][34];
    __shared__ float Bs[8][68];
    const int tid = threadIdx.x;
    const int bn = blockIdx.x * 64;
    const int bm = blockIdx.y * 32;
    const int k0 = blockIdx.z * 128;
    const bool is_out = (bn < 64);

    const int tx = tid & 15;
    const int ty = tid >> 4;
    const int sa_k = tid & 7;
    const int sa_m = tid >> 3;
    const int sb_n = tid >> 2;
    const int sb_k = (tid & 3) * 2;
    const int qa_k = tid >> 5;
    const int qa_n = (tid & 31) * 2;

    float acc[2][4];
#pragma unroll
    for (int i = 0; i < 2; i++)
#pragma unroll
        for (int j = 0; j < 4; j++) acc[i][j] = 0.f;

    for (int kt = 0; kt < 16; kt++) {
        const int kb = k0 + kt * 8;
        {
            int m = bm + sa_m;
            int k = kb + sa_k;
            As[sa_k][sa_m] = tanhf(hpre_cur[(size_t)m * 512 + k] + b_ih[k] + b_hh[k]);
        }
        if (is_out) {
            int n = bn + sb_n;
#pragma unroll
            for (int i = 0; i < 2; i++) {
                int k = kb + sb_k + i;
                Bs[sb_k + i][sb_n] = Wo[(size_t)n * 512 + k];
            }
        } else {
            int k = kb + qa_k;
            int n = bn - 64 + qa_n;
#pragma unroll
            for (int i = 0; i < 2; i++)
                Bs[qa_k][qa_n + i] = Wa[(size_t)k * 512 + n + i];
        }
        __syncthreads();
#pragma unroll
        for (int kk = 0; kk < 8; kk++) {
            float a0 = As[kk][ty * 2], a1 = As[kk][ty * 2 + 1];
            float b0 = Bs[kk][tx * 4], b1 = Bs[kk][tx * 4 + 1];
            float b2 = Bs[kk][tx * 4 + 2], b3 = Bs[kk][tx * 4 + 3];
            acc[0][0] += a0 * b0; acc[0][1] += a0 * b1;
            acc[0][2] += a0 * b2; acc[0][3] += a0 * b3;
            acc[1][0] += a1 * b0; acc[1][1] += a1 * b1;
            acc[1][2] += a1 * b2; acc[1][3] += a1 * b3;
        }
        __syncthreads();
    }
#pragma unroll
    for (int i = 0; i < 2; i++) {
        int m = bm + ty * 2 + i;
#pragma unroll
        for (int j = 0; j < 4; j++) {
            int n = bn + tx * 4 + j;
            if (is_out) atomicAdd(&ob[m * 64 + n], acc[i][j]);
            else        atomicAdd(&qpre[(size_t)m * 512 + (n - 64)], acc[i][j]);
        }
    }
}

// ---------------------------------------------------------------------------
// k_argmax: final-step dout write (t=62). out = ob + bo; dout[b][n][t].
// ---------------------------------------------------------------------------
__global__ __launch_bounds__(256) void k_argmax(const float* __restrict__ ob,
                                                const float* __restrict__ bo,
                                                float* __restrict__ dout, int t,
                                                float* __restrict__ x)
{
    const int b = blockIdx.x * 4 + (threadIdx.x >> 6);
    const int l = threadIdx.x & 63;
    float v = ob[b * 64 + l] + bo[l];
    dout[(size_t)b * (OO * NSTEP) + l * NSTEP + t] = v;
    int bi = l;
    float bv = v;
#pragma unroll
    for (int off = 1; off < 64; off <<= 1) {
        float ov = __shfl_xor(bv, off);
        int oi = __shfl_xor(bi, off);
        if (ov > bv || (ov == bv && oi < bi)) { bv = ov; bi = oi; }
    }
    x[b * 64 + l] = (l == bi) ? 1.0f : 0.0f;
}

// ---------------------------------------------------------------------------
extern "C" void kernel_launch(void* const* d_in, const int* in_sizes, int n_in,
                              void* d_out, int out_size, void* d_ws, size_t ws_size,
                              hipStream_t stream)
{
    const float* sos  = (const float*)d_in[0];
    const float* h0   = (const float*)d_in[1];
    const float* enc  = (const float*)d_in[2];
    const float* Wa   = (const float*)d_in[3];
    const float* ba   = (const float*)d_in[4];
    const float* vvec = (const float*)d_in[5];
    const float* W_ih = (const float*)d_in[6];
    const float* b_ih = (const float*)d_in[7];
    const float* W_hh = (const float*)d_in[8];
    const float* b_hh = (const float*)d_in[9];
    const float* Wo   = (const float*)d_in[10];
    const float* bo   = (const float*)d_in[11];
    float* out = (float*)d_out;

    // Workspace: exactly 34,111,488 floats (136.4 MB) — the known-good budget.
    float* ws = (float*)d_ws;
    float* EW    = ws; ws += (size_t)SS * BB * HH;   // 33,554,432  [b][s][h]
    float* qpre  = ws; ws += BB * HH;                // pre-bias q
    float* ctx   = ws; ws += BB * HH;
    float* hpre0 = ws; ws += BB * HH;                // pre-activation h
    float* hpre1 = ws; ws += BB * HH;
    float* xb    = ws; ws += BB * OO;
    float* ob    = ws; ws += BB * OO;                // pre-bias out

    // ---- Precompute ----
    k_ew_gemm<<<dim3(512, 4), 256, 0, stream>>>(enc, Wa + 512 * 512, EW);
    k_qinit<<<dim3(16, 8), 256, 0, stream>>>(h0, Wa, qpre);

    // ---- 63 decode steps (3 kernels/step; argmax folded into k_attn) ----
    for (int t = 0; t < NSTEP; t++) {
        float* hpre_out = (t & 1) ? hpre1 : hpre0;
        float* hpre_in  = (t & 1) ? hpre0 : hpre1;   // valid for t>=1
        const float* xin = (t == 0) ? sos : xb;

        // prev-step argmax/dout + attention (+ zero hpre_out)
        k_attn<<<256, 1024, 0, stream>>>(EW, enc, qpre, ba, vvec, ctx,
                                         hpre_out, ob, bo, out, xb, t);

        // hpre_out += [x|ctx|h_prev] @ Wcat^T   (+ zero qpre, ob)
        k_h<<<dim3(8, 8, 8), 256, 0, stream>>>(xin, ctx, hpre_in, h0, (t == 0) ? 1 : 0,
                                               W_ih, W_hh, b_ih, b_hh,
                                               hpre_out, qpre, ob);

        // ob += h @ Wo^T ; qpre += h @ Wa_top
        k_outq<<<dim3(9, 8, 4), 256, 0, stream>>>(hpre_out, b_ih, b_hh,
                                                  Wo, Wa, ob, qpre);
    }

    // final step's dout (t = 62)
    k_argmax<<<64, 256, 0, stream>>>(ob, bo, out, NSTEP - 1, xb);
}